// Round 3
// baseline (656.765 us; speedup 1.0000x reference)
//
#include <hip/hip_runtime.h>
#include <hip/hip_bf16.h>
#include <math.h>

// GanDTI forward. B=4096, N_ATOMS=50, FEAT=40, GNN_DEPTH=3, MLP_DEPTH=2.
//
// k_heavy: 2048 blocks x 192 threads (3 waves). NO __syncthreads (each wave's
// LDS region is private; same-wave LDS ops are in-order on CDNA).
//   wave 0: GNN for sample 2b      (1 wave per sample, 9x4 reg tile)
//   wave 1: GNN for sample 2b+1
//   wave 2 (blocks<1024): A69 [B,1001,30] stream -> a256, 4 samples
// LDS 53.8 KB/block -> 3 blocks/CU, 9 waves/CU.
// k_tail: 256 blocks x 256 threads, 16 samples/block; p256 in registers.

#define BATCH 4096
#define SA 52   // A row stride (floats)
#define SC 40   // comp/h row stride

__global__ __launch_bounds__(192) void k_heavy(
    const int* __restrict__ atoms, const float* __restrict__ A,
    const float* __restrict__ A69, const float* __restrict__ emb,
    const float* __restrict__ Wg, const float* __restrict__ bg,
    const float* __restrict__ W1, const float* __restrict__ b1,
    const float* __restrict__ W2, const float* __restrict__ b2,
    float* __restrict__ ws_cv, float* __restrict__ ws_a256)
{
    // per-wave regions: wave0 @0, wave1 @6600 (A 2600 + comp 2000 + h 2000),
    // a69 buf @13200 [4][64]
    __shared__ float sm[13456];
    const int tid  = threadIdx.x;
    const int lane = tid & 63;
    const int wv   = tid >> 6;
    const int blk  = blockIdx.x;

    if (wv < 2) {
        // ================= GNN: one wave, one sample =================
        const int b = blk * 2 + wv;
        float* a_s  = sm + wv * 6600;
        float* comp = a_s + 2600;
        float* h_s  = comp + 2000;

        // stage A (coalesced global, b32 LDS writes, padded stride SA)
        for (int i = lane; i < 2500; i += 64) {
            const int n = i / 50, m = i - n * 50;
            a_s[n * SA + m] = A[(size_t)b * 2500 + i];
        }
        // stage emb -> comp (b128)
        for (int i = lane; i < 500; i += 64) {
            const int n = i / 10, f4 = i - n * 10;
            const int row = atoms[b * 50 + n];
            *(float4*)(comp + n * SC + f4 * 4) = *(const float4*)(emb + row * 40 + f4 * 4);
        }
        // residual column sum (lanes 0..39) — same-wave in-order LDS
        float res_sum = 0.f;
        if (lane < 40) {
            for (int n = 0; n < 50; ++n) res_sum += comp[n * SC + lane];
        }

        const int rg = lane / 10;            // 0..5 (row group, rows rg+6k)
        const int fg = lane - rg * 10;       // 0..9
        const int f0 = fg * 4;
        const bool actv = (lane < 60);

        float acc[9][4];

        for (int l = 0; l < 3; ++l) {
            const float* wgl = Wg + l * 1600;
            if (actv) {
                // ---- m1: h = leaky(comp @ Wg[l] + bg[l]) ----
                #pragma unroll
                for (int k = 0; k < 9; ++k)
                    #pragma unroll
                    for (int c = 0; c < 4; ++c) acc[k][c] = 0.f;
                #pragma unroll
                for (int j4 = 0; j4 < 10; ++j4) {
                    float wv4[4][4];
                    #pragma unroll
                    for (int u = 0; u < 4; ++u)
                        *(float4*)wv4[u] = *(const float4*)(wgl + (j4 * 4 + u) * 40 + f0);
                    #pragma unroll
                    for (int k = 0; k < 9; ++k) {
                        if (k < 8 || rg < 2) {
                            const int n = rg + 6 * k;
                            float cv[4];
                            *(float4*)cv = *(float4*)(comp + n * SC + j4 * 4);
                            #pragma unroll
                            for (int u = 0; u < 4; ++u)
                                #pragma unroll
                                for (int c = 0; c < 4; ++c)
                                    acc[k][c] = fmaf(cv[u], wv4[u][c], acc[k][c]);
                        }
                    }
                }
                float bgv[4];
                *(float4*)bgv = *(const float4*)(bg + l * 40 + f0);
                #pragma unroll
                for (int k = 0; k < 9; ++k) {
                    if (k < 8 || rg < 2) {
                        const int n = rg + 6 * k;
                        float hv[4];
                        #pragma unroll
                        for (int c = 0; c < 4; ++c) {
                            const float s = acc[k][c] + bgv[c];
                            hv[c] = s > 0.f ? s : 0.01f * s;
                        }
                        *(float4*)(h_s + n * SC + f0) = *(float4*)hv;
                    }
                }
                // ---- m2: comp += A @ h ----
                #pragma unroll
                for (int k = 0; k < 9; ++k)
                    #pragma unroll
                    for (int c = 0; c < 4; ++c) acc[k][c] = 0.f;
                #pragma unroll
                for (int m4 = 0; m4 < 12; ++m4) {
                    float hv4[4][4];
                    #pragma unroll
                    for (int u = 0; u < 4; ++u)
                        *(float4*)hv4[u] = *(float4*)(h_s + (m4 * 4 + u) * SC + f0);
                    #pragma unroll
                    for (int k = 0; k < 9; ++k) {
                        if (k < 8 || rg < 2) {
                            const int n = rg + 6 * k;
                            float av[4];
                            *(float4*)av = *(float4*)(a_s + n * SA + m4 * 4);
                            #pragma unroll
                            for (int u = 0; u < 4; ++u)
                                #pragma unroll
                                for (int c = 0; c < 4; ++c)
                                    acc[k][c] = fmaf(av[u], hv4[u][c], acc[k][c]);
                        }
                    }
                }
                // tail m = 48, 49
                {
                    float h48[4], h49[4];
                    *(float4*)h48 = *(float4*)(h_s + 48 * SC + f0);
                    *(float4*)h49 = *(float4*)(h_s + 49 * SC + f0);
                    #pragma unroll
                    for (int k = 0; k < 9; ++k) {
                        if (k < 8 || rg < 2) {
                            const int n = rg + 6 * k;
                            float a2[2];
                            *(float2*)a2 = *(float2*)(a_s + n * SA + 48);
                            #pragma unroll
                            for (int c = 0; c < 4; ++c) {
                                acc[k][c] = fmaf(a2[0], h48[c], acc[k][c]);
                                acc[k][c] = fmaf(a2[1], h49[c], acc[k][c]);
                            }
                        }
                    }
                }
                #pragma unroll
                for (int k = 0; k < 9; ++k) {
                    if (k < 8 || rg < 2) {
                        const int n = rg + 6 * k;
                        float cv[4];
                        *(float4*)cv = *(float4*)(comp + n * SC + f0);
                        #pragma unroll
                        for (int c = 0; c < 4; ++c) cv[c] += acc[k][c];
                        *(float4*)(comp + n * SC + f0) = *(float4*)cv;
                    }
                }
            }
        }
        // mean over atoms + residual
        if (lane < 40) {
            float s = res_sum;
            for (int n = 0; n < 50; ++n) s += comp[n * SC + lane];
            ws_cv[(size_t)b * 40 + lane] = s * 0.02f;
        }
    } else {
        // ================= A69 stream: 4 samples, wave-private =================
        if (blk >= 1024) return;
        const int s0_ = blk * 4;
        float* a69s = sm + 13200;    // [4][64]
        const int c0 = lane * 4;

        float w1r[30];
        #pragma unroll
        for (int k = 0; k < 15; ++k) {
            float2 t = ((const float2*)W1)[k];
            w1r[2 * k] = t.x; w1r[2 * k + 1] = t.y;
        }
        const float b1v = b1[0];

        float acc[4][4];
        #pragma unroll
        for (int s = 0; s < 4; ++s)
            #pragma unroll
            for (int c = 0; c < 4; ++c) acc[s][c] = 0.f;

        for (int ch = 0; ch < 16; ++ch) {
            const int j0 = ch * 64;
            const int nr = (ch == 15) ? 41 : 64;
            // stage: lane handles row j0+lane for all 4 samples
            if (lane < nr) {
                #pragma unroll
                for (int s = 0; s < 4; ++s) {
                    const float2* p = (const float2*)(A69 + ((size_t)(s0_ + s) * 1001 + j0 + lane) * 30);
                    float v = b1v;
                    #pragma unroll
                    for (int k = 0; k < 15; ++k) {
                        float2 t = p[k];
                        v = fmaf(t.x, w1r[2 * k], v);
                        v = fmaf(t.y, w1r[2 * k + 1], v);
                    }
                    a69s[s * 64 + lane] = v;
                }
            }
            // accumulate (same-wave in-order LDS: writes above visible)
            const int nr4 = nr >> 2;
            #pragma unroll 4
            for (int jj4 = 0; jj4 < nr4; ++jj4) {
                float av[4][4];
                #pragma unroll
                for (int s = 0; s < 4; ++s)
                    *(float4*)av[s] = *(float4*)(a69s + s * 64 + jj4 * 4);
                #pragma unroll
                for (int u = 0; u < 4; ++u) {
                    float w2v[4];
                    *(float4*)w2v = *(const float4*)(W2 + (size_t)(j0 + jj4 * 4 + u) * 256 + c0);
                    #pragma unroll
                    for (int s = 0; s < 4; ++s)
                        #pragma unroll
                        for (int c = 0; c < 4; ++c)
                            acc[s][c] = fmaf(av[s][u], w2v[c], acc[s][c]);
                }
            }
            if (nr & 3) {   // ch==15: one extra row (j = 1000)
                float w2v[4];
                *(float4*)w2v = *(const float4*)(W2 + (size_t)1000 * 256 + c0);
                #pragma unroll
                for (int s = 0; s < 4; ++s) {
                    const float a1 = a69s[s * 64 + 40];
                    #pragma unroll
                    for (int c = 0; c < 4; ++c) acc[s][c] = fmaf(a1, w2v[c], acc[s][c]);
                }
            }
        }
        float b2v[4];
        *(float4*)b2v = *(const float4*)(b2 + c0);
        #pragma unroll
        for (int s = 0; s < 4; ++s) {
            float o[4];
            #pragma unroll
            for (int c = 0; c < 4; ++c) o[c] = acc[s][c] + b2v[c];
            *(float4*)(ws_a256 + (size_t)(s0_ + s) * 256 + c0) = *(float4*)o;
        }
    }
}

__global__ __launch_bounds__(256) void k_tail(
    const float* __restrict__ protein,
    const float* __restrict__ W3, const float* __restrict__ b3,
    const float* __restrict__ Wp, const float* __restrict__ bp,
    const float* __restrict__ Watt, const float* __restrict__ batt,
    const float* __restrict__ Wm, const float* __restrict__ bm,
    const float* __restrict__ Wo, const float* __restrict__ bo,
    const float* __restrict__ ws_cv, const float* __restrict__ ws_a256,
    float* __restrict__ out)
{
    const int PC = 520;
    __shared__ float pc[16 * 520];
    __shared__ float p40s[16 * 40];
    __shared__ float phs[16 * 40];
    __shared__ float wts[16];
    __shared__ float cps[2][16 * 84];
    const int tid  = threadIdx.x;
    const int lane = tid & 63;
    const int wv   = tid >> 6;
    const int blk  = blockIdx.x;
    const int c0   = lane * 4;

    // ---- p256 = protein @ W3 + b3, fully in registers (4 samples per wave) ----
    {
        float acc[4][4];
        #pragma unroll
        for (int s = 0; s < 4; ++s)
            #pragma unroll
            for (int c = 0; c < 4; ++c) acc[s][c] = 0.f;
        const float* prot = protein + (size_t)(blk * 16 + wv * 4) * 512;
        for (int j4 = 0; j4 < 128; ++j4) {
            float pv[4][4];
            #pragma unroll
            for (int s = 0; s < 4; ++s)
                *(float4*)pv[s] = *(const float4*)(prot + (size_t)s * 512 + j4 * 4);
            #pragma unroll
            for (int u = 0; u < 4; ++u) {
                float w3v[4];
                *(float4*)w3v = *(const float4*)(W3 + (size_t)(j4 * 4 + u) * 256 + c0);
                #pragma unroll
                for (int s = 0; s < 4; ++s)
                    #pragma unroll
                    for (int c = 0; c < 4; ++c)
                        acc[s][c] = fmaf(pv[s][u], w3v[c], acc[s][c]);
            }
        }
        float b3v[4];
        *(float4*)b3v = *(const float4*)(b3 + c0);
        #pragma unroll
        for (int s = 0; s < 4; ++s) {
            const int g = wv * 4 + s;
            float o[4];
            #pragma unroll
            for (int c = 0; c < 4; ++c) o[c] = acc[s][c] + b3v[c];
            *(float4*)(pc + g * PC + 256 + c0) = *(float4*)o;
            *(float4*)(pc + g * PC + c0) =
                *(const float4*)(ws_a256 + (size_t)(blk * 16 + g) * 256 + c0);
        }
    }
    __syncthreads();

    // ---- p40 = pcat @ Wp + bp  (80 tasks: (f8,g), 8 cols each) ----
    if (tid < 80) {
        const int f8 = tid >> 4, g = tid & 15, fo = f8 * 8;
        float a8[8];
        #pragma unroll
        for (int c = 0; c < 8; ++c) a8[c] = bp[fo + c];
        for (int j4 = 0; j4 < 128; ++j4) {
            float pv[4];
            *(float4*)pv = *(float4*)(pc + g * PC + j4 * 4);
            #pragma unroll
            for (int u = 0; u < 4; ++u) {
                const int j = j4 * 4 + u;
                float wa[4], wb[4];
                *(float4*)wa = *(const float4*)(Wp + j * 40 + fo);
                *(float4*)wb = *(const float4*)(Wp + j * 40 + fo + 4);
                #pragma unroll
                for (int c = 0; c < 4; ++c) {
                    a8[c]     = fmaf(pv[u], wa[c], a8[c]);
                    a8[4 + c] = fmaf(pv[u], wb[c], a8[4 + c]);
                }
            }
        }
        *(float4*)(p40s + g * 40 + fo)     = *(float4*)a8;
        *(float4*)(p40s + g * 40 + fo + 4) = *(float4*)(a8 + 4);
    }
    __syncthreads();

    // ---- protein_h = relu(p40 @ Watt + batt) ----
    for (int it = tid; it < 640; it += 256) {
        const int g = it / 40, f = it - g * 40;
        float s = batt[f];
        #pragma unroll
        for (int j4 = 0; j4 < 10; ++j4) {
            float pv[4];
            *(float4*)pv = *(float4*)(p40s + g * 40 + j4 * 4);
            #pragma unroll
            for (int u = 0; u < 4; ++u)
                s = fmaf(pv[u], Watt[(j4 * 4 + u) * 40 + f], s);
        }
        phs[it] = s > 0.f ? s : 0.f;
    }
    __syncthreads();

    // ---- attention weight ----
    if (tid < 16) {
        float m = 0.f;
        #pragma unroll
        for (int f4 = 0; f4 < 10; ++f4) {
            float cv[4], ph[4];
            *(float4*)cv = *(const float4*)(ws_cv + (size_t)(blk * 16 + tid) * 40 + f4 * 4);
            *(float4*)ph = *(float4*)(phs + tid * 40 + f4 * 4);
            #pragma unroll
            for (int c = 0; c < 4; ++c) m = fmaf(cv[c], ph[c], m);
        }
        wts[tid] = tanhf(m);
    }
    __syncthreads();

    // ---- cp = [compound_vec | weights * protein_h] ----
    for (int it = tid; it < 1280; it += 256) {
        const int g = it / 80, f = it - g * 80;
        const float v = (f < 40) ? ws_cv[(size_t)(blk * 16 + g) * 40 + f]
                                 : wts[g] * phs[g * 40 + (f - 40)];
        cps[0][g * 84 + f] = v;
    }
    __syncthreads();

    // ---- MLP head ----
    int cb = 0;
    for (int l = 0; l < 2; ++l) {
        for (int it = tid; it < 1280; it += 256) {
            const int g = it / 80, kk = it - g * 80;
            float s = bm[l * 80 + kk];
            #pragma unroll
            for (int j4 = 0; j4 < 20; ++j4) {
                float cv[4];
                *(float4*)cv = *(float4*)(cps[cb] + g * 84 + j4 * 4);
                #pragma unroll
                for (int u = 0; u < 4; ++u)
                    s = fmaf(cv[u], Wm[l * 6400 + (j4 * 4 + u) * 80 + kk], s);
            }
            cps[cb ^ 1][g * 84 + kk] = s > 0.f ? s : 0.f;
        }
        __syncthreads();
        cb ^= 1;
    }
    if (tid < 16) {
        float s = bo[0];
        #pragma unroll
        for (int j4 = 0; j4 < 20; ++j4) {
            float cv[4], wo[4];
            *(float4*)cv = *(float4*)(cps[cb] + tid * 84 + j4 * 4);
            *(float4*)wo = *(const float4*)(Wo + j4 * 4);
            #pragma unroll
            for (int u = 0; u < 4; ++u) s = fmaf(cv[u], wo[u], s);
        }
        out[blk * 16 + tid] = s;
    }
}

extern "C" void kernel_launch(void* const* d_in, const int* in_sizes, int n_in,
                              void* d_out, int out_size, void* d_ws, size_t ws_size,
                              hipStream_t stream) {
    const int*   atoms   = (const int*)d_in[0];
    const float* A       = (const float*)d_in[1];
    const float* A69     = (const float*)d_in[2];
    const float* protein = (const float*)d_in[3];
    const float* emb     = (const float*)d_in[4];
    const float* Wg      = (const float*)d_in[5];
    const float* bg      = (const float*)d_in[6];
    const float* Watt    = (const float*)d_in[7];
    const float* batt    = (const float*)d_in[8];
    const float* W1      = (const float*)d_in[9];
    const float* b1      = (const float*)d_in[10];
    const float* W2      = (const float*)d_in[11];
    const float* b2      = (const float*)d_in[12];
    const float* W3      = (const float*)d_in[13];
    const float* b3      = (const float*)d_in[14];
    const float* Wp      = (const float*)d_in[15];
    const float* bp      = (const float*)d_in[16];
    const float* Wm      = (const float*)d_in[17];
    const float* bm      = (const float*)d_in[18];
    const float* Wo      = (const float*)d_in[19];
    const float* bo      = (const float*)d_in[20];

    float* ws_cv   = (float*)d_ws;                  // [4096][40]
    float* ws_a256 = ws_cv + (size_t)BATCH * 40;    // [4096][256]
    float* outp    = (float*)d_out;

    k_heavy<<<dim3(2048), dim3(192), 0, stream>>>(
        atoms, A, A69, emb, Wg, bg, W1, b1, W2, b2, ws_cv, ws_a256);
    k_tail<<<dim3(256), dim3(256), 0, stream>>>(
        protein, W3, b3, Wp, bp, Watt, batt, Wm, bm, Wo, bo, ws_cv, ws_a256, outp);
}

// Round 4
// 404.143 us; speedup vs baseline: 1.6251x; 1.6251x over previous
//
#include <hip/hip_runtime.h>
#include <hip/hip_bf16.h>
#include <math.h>

// GanDTI forward. B=4096, N_ATOMS=50, FEAT=40, GNN_DEPTH=3, MLP_DEPTH=2.
//
// k_heavy: 4224 blocks x 256 threads.
//   blocks [0,128):    A69 stream. 4 waves x 8 samples; per-row W1-dot in lane
//                      registers -> LDS [64][12]; accumulate = 2 broadcast b128
//                      + 1 W2 b128 + 32 FMA per row. (round-3 scheme, fixed regs)
//   blocks [128,4224): GNN, one sample/block — EXACT round-2 structure
//                      (2x4 tile, 4 waves, 34.4 KB LDS, VGPR ~68, no spills).
// k_tail: 256 blocks x 256 threads, 16 samples/block; p256 in registers.

#define BATCH 4096
#define SA 52   // A row stride (floats)
#define SC 44   // comp/h row stride

__global__ __launch_bounds__(256) void k_heavy(
    const int* __restrict__ atoms, const float* __restrict__ A,
    const float* __restrict__ A69, const float* __restrict__ emb,
    const float* __restrict__ Wg, const float* __restrict__ bg,
    const float* __restrict__ W1, const float* __restrict__ b1,
    const float* __restrict__ W2, const float* __restrict__ b2,
    float* __restrict__ ws_cv, float* __restrict__ ws_a256)
{
    __shared__ float sm[8600];      // GNN: full; A69: [4 waves][64*12]
    const int tid  = threadIdx.x;
    const int blk  = blockIdx.x;

    if (blk < 128) {
        // ================= A69 stream: 8 samples per wave =================
        const int lane = tid & 63;
        const int wv   = tid >> 6;
        const int s0_  = blk * 32 + wv * 8;
        float* a69s = sm + wv * 768;          // [64][12]
        const int c0 = lane * 4;

        float w1r[30];
        #pragma unroll
        for (int k = 0; k < 15; ++k) {
            float2 t = ((const float2*)W1)[k];
            w1r[2 * k] = t.x; w1r[2 * k + 1] = t.y;
        }
        const float b1v = b1[0];

        float acc[8][4];
        #pragma unroll
        for (int s = 0; s < 8; ++s)
            #pragma unroll
            for (int c = 0; c < 4; ++c) acc[s][c] = 0.f;

        for (int ch = 0; ch < 16; ++ch) {
            const int j0 = ch * 64;
            const int nr = (ch == 15) ? 41 : 64;
            // stage: lane computes W1-dot of row j0+lane for its 8 samples
            if (lane < nr) {
                #pragma unroll
                for (int s = 0; s < 8; ++s) {
                    const float2* p = (const float2*)(A69 + ((size_t)(s0_ + s) * 1001 + j0 + lane) * 30);
                    float v = b1v;
                    #pragma unroll
                    for (int k = 0; k < 15; ++k) {
                        float2 t = p[k];
                        v = fmaf(t.x, w1r[2 * k], v);
                        v = fmaf(t.y, w1r[2 * k + 1], v);
                    }
                    a69s[lane * 12 + s] = v;
                }
            }
            // accumulate: broadcast LDS reads (same-wave in-order)
            for (int jj = 0; jj < nr; ++jj) {
                float av[8];
                *(float4*)av       = *(float4*)(a69s + jj * 12);
                *(float4*)(av + 4) = *(float4*)(a69s + jj * 12 + 4);
                float w2v[4];
                *(float4*)w2v = *(const float4*)(W2 + (size_t)(j0 + jj) * 256 + c0);
                #pragma unroll
                for (int s = 0; s < 8; ++s)
                    #pragma unroll
                    for (int c = 0; c < 4; ++c)
                        acc[s][c] = fmaf(av[s], w2v[c], acc[s][c]);
            }
        }
        float b2v[4];
        *(float4*)b2v = *(const float4*)(b2 + c0);
        #pragma unroll
        for (int s = 0; s < 8; ++s) {
            float o[4];
            #pragma unroll
            for (int c = 0; c < 4; ++c) o[c] = acc[s][c] + b2v[c];
            *(float4*)(ws_a256 + (size_t)(s0_ + s) * 256 + c0) = *(float4*)o;
        }
    } else {
        // ================= GNN: one sample per block (round-2 code) =================
        const int b = blk - 128;
        float* a_s  = sm;          // [50][SA]
        float* comp = sm + 2600;   // [50][SC]
        float* h_s  = sm + 4800;   // [50][SC]
        float* wg_s = sm + 7000;   // [40][40]

        for (int idx = tid; idx < 2500; idx += 256) {
            const int n = idx / 50, m = idx - n * 50;
            a_s[n * SA + m] = A[(size_t)b * 2500 + idx];
        }
        for (int idx = tid; idx < 500; idx += 256) {
            const int n = idx / 10, f4 = idx - n * 10;
            const int row = atoms[b * 50 + n];
            *(float4*)(comp + n * SC + f4 * 4) = *(const float4*)(emb + row * 40 + f4 * 4);
        }
        if (tid < 256) *(float4*)(wg_s + tid * 4) = *(const float4*)(Wg + tid * 4);
        if (tid < 144) *(float4*)(wg_s + 1024 + tid * 4) = *(const float4*)(Wg + 1024 + tid * 4);
        __syncthreads();

        float res_sum = 0.f;
        if (tid < 40) {
            for (int n = 0; n < 50; ++n) res_sum += comp[n * SC + tid];
        }

        const int np = tid / 10, fg = tid - np * 10;
        const int n0 = np * 2, f0 = fg * 4;
        const bool act = (tid < 250);

        for (int l = 0; l < 3; ++l) {
            float4 wgp0, wgp1;
            if (l < 2) {
                wgp0 = *(const float4*)(Wg + (l + 1) * 1600 + tid * 4);
                if (tid < 144) wgp1 = *(const float4*)(Wg + (l + 1) * 1600 + 1024 + tid * 4);
            }
            if (act) {
                float4 bgv = *(const float4*)(bg + l * 40 + f0);
                float acc0[4] = {bgv.x, bgv.y, bgv.z, bgv.w};
                float acc1[4] = {bgv.x, bgv.y, bgv.z, bgv.w};
                #pragma unroll
                for (int j4 = 0; j4 < 40; j4 += 4) {
                    float c0a[4], c1a[4];
                    *(float4*)c0a = *(float4*)(comp + n0 * SC + j4);
                    *(float4*)c1a = *(float4*)(comp + n0 * SC + SC + j4);
                    #pragma unroll
                    for (int u = 0; u < 4; ++u) {
                        float wv[4];
                        *(float4*)wv = *(float4*)(wg_s + (j4 + u) * 40 + f0);
                        #pragma unroll
                        for (int q = 0; q < 4; ++q) {
                            acc0[q] = fmaf(c0a[u], wv[q], acc0[q]);
                            acc1[q] = fmaf(c1a[u], wv[q], acc1[q]);
                        }
                    }
                }
                float h0[4], h1[4];
                #pragma unroll
                for (int q = 0; q < 4; ++q) {
                    h0[q] = acc0[q] > 0.f ? acc0[q] : 0.01f * acc0[q];
                    h1[q] = acc1[q] > 0.f ? acc1[q] : 0.01f * acc1[q];
                }
                *(float4*)(h_s + n0 * SC + f0) = *(float4*)h0;
                *(float4*)(h_s + n0 * SC + SC + f0) = *(float4*)h1;
            }
            __syncthreads();
            if (l < 2) {
                *(float4*)(wg_s + tid * 4) = wgp0;
                if (tid < 144) *(float4*)(wg_s + 1024 + tid * 4) = wgp1;
            }
            if (act) {
                float acc0[4] = {0, 0, 0, 0}, acc1[4] = {0, 0, 0, 0};
                #pragma unroll
                for (int m4 = 0; m4 < 48; m4 += 4) {
                    float a0a[4], a1a[4];
                    *(float4*)a0a = *(float4*)(a_s + n0 * SA + m4);
                    *(float4*)a1a = *(float4*)(a_s + n0 * SA + SA + m4);
                    #pragma unroll
                    for (int u = 0; u < 4; ++u) {
                        float hv[4];
                        *(float4*)hv = *(float4*)(h_s + (m4 + u) * SC + f0);
                        #pragma unroll
                        for (int q = 0; q < 4; ++q) {
                            acc0[q] = fmaf(a0a[u], hv[q], acc0[q]);
                            acc1[q] = fmaf(a1a[u], hv[q], acc1[q]);
                        }
                    }
                }
                #pragma unroll
                for (int m = 48; m < 50; ++m) {
                    const float a0 = a_s[n0 * SA + m], a1 = a_s[n0 * SA + SA + m];
                    float hv[4];
                    *(float4*)hv = *(float4*)(h_s + m * SC + f0);
                    #pragma unroll
                    for (int q = 0; q < 4; ++q) {
                        acc0[q] = fmaf(a0, hv[q], acc0[q]);
                        acc1[q] = fmaf(a1, hv[q], acc1[q]);
                    }
                }
                float c0a[4], c1a[4];
                *(float4*)c0a = *(float4*)(comp + n0 * SC + f0);
                *(float4*)c1a = *(float4*)(comp + n0 * SC + SC + f0);
                #pragma unroll
                for (int q = 0; q < 4; ++q) { c0a[q] += acc0[q]; c1a[q] += acc1[q]; }
                *(float4*)(comp + n0 * SC + f0) = *(float4*)c0a;
                *(float4*)(comp + n0 * SC + SC + f0) = *(float4*)c1a;
            }
            __syncthreads();
        }
        if (tid < 40) {
            float s = res_sum;
            for (int n = 0; n < 50; ++n) s += comp[n * SC + tid];
            ws_cv[(size_t)b * 40 + tid] = s * 0.02f;
        }
    }
}

__global__ __launch_bounds__(256) void k_tail(
    const float* __restrict__ protein,
    const float* __restrict__ W3, const float* __restrict__ b3,
    const float* __restrict__ Wp, const float* __restrict__ bp,
    const float* __restrict__ Watt, const float* __restrict__ batt,
    const float* __restrict__ Wm, const float* __restrict__ bm,
    const float* __restrict__ Wo, const float* __restrict__ bo,
    const float* __restrict__ ws_cv, const float* __restrict__ ws_a256,
    float* __restrict__ out)
{
    const int PC = 520;
    __shared__ float pc[16 * 520];
    __shared__ float p40s[16 * 40];
    __shared__ float phs[16 * 40];
    __shared__ float wts[16];
    __shared__ float cps[2][16 * 84];
    const int tid  = threadIdx.x;
    const int lane = tid & 63;
    const int wv   = tid >> 6;
    const int blk  = blockIdx.x;
    const int c0   = lane * 4;

    // ---- p256 = protein @ W3 + b3, in registers (4 samples per wave) ----
    {
        float acc[4][4];
        #pragma unroll
        for (int s = 0; s < 4; ++s)
            #pragma unroll
            for (int c = 0; c < 4; ++c) acc[s][c] = 0.f;
        const float* prot = protein + (size_t)(blk * 16 + wv * 4) * 512;
        for (int j4 = 0; j4 < 128; ++j4) {
            float pv[4][4];
            #pragma unroll
            for (int s = 0; s < 4; ++s)
                *(float4*)pv[s] = *(const float4*)(prot + (size_t)s * 512 + j4 * 4);
            #pragma unroll
            for (int u = 0; u < 4; ++u) {
                float w3v[4];
                *(float4*)w3v = *(const float4*)(W3 + (size_t)(j4 * 4 + u) * 256 + c0);
                #pragma unroll
                for (int s = 0; s < 4; ++s)
                    #pragma unroll
                    for (int c = 0; c < 4; ++c)
                        acc[s][c] = fmaf(pv[s][u], w3v[c], acc[s][c]);
            }
        }
        float b3v[4];
        *(float4*)b3v = *(const float4*)(b3 + c0);
        #pragma unroll
        for (int s = 0; s < 4; ++s) {
            const int g = wv * 4 + s;
            float o[4];
            #pragma unroll
            for (int c = 0; c < 4; ++c) o[c] = acc[s][c] + b3v[c];
            *(float4*)(pc + g * PC + 256 + c0) = *(float4*)o;
            *(float4*)(pc + g * PC + c0) =
                *(const float4*)(ws_a256 + (size_t)(blk * 16 + g) * 256 + c0);
        }
    }
    __syncthreads();

    // ---- p40 = pcat @ Wp + bp  (80 tasks: (f8,g), 8 cols each) ----
    if (tid < 80) {
        const int f8 = tid >> 4, g = tid & 15, fo = f8 * 8;
        float a8[8];
        #pragma unroll
        for (int c = 0; c < 8; ++c) a8[c] = bp[fo + c];
        for (int j4 = 0; j4 < 128; ++j4) {
            float pv[4];
            *(float4*)pv = *(float4*)(pc + g * PC + j4 * 4);
            #pragma unroll
            for (int u = 0; u < 4; ++u) {
                const int j = j4 * 4 + u;
                float wa[4], wb[4];
                *(float4*)wa = *(const float4*)(Wp + j * 40 + fo);
                *(float4*)wb = *(const float4*)(Wp + j * 40 + fo + 4);
                #pragma unroll
                for (int c = 0; c < 4; ++c) {
                    a8[c]     = fmaf(pv[u], wa[c], a8[c]);
                    a8[4 + c] = fmaf(pv[u], wb[c], a8[4 + c]);
                }
            }
        }
        *(float4*)(p40s + g * 40 + fo)     = *(float4*)a8;
        *(float4*)(p40s + g * 40 + fo + 4) = *(float4*)(a8 + 4);
    }
    __syncthreads();

    // ---- protein_h = relu(p40 @ Watt + batt) ----
    for (int it = tid; it < 640; it += 256) {
        const int g = it / 40, f = it - g * 40;
        float s = batt[f];
        #pragma unroll
        for (int j4 = 0; j4 < 10; ++j4) {
            float pv[4];
            *(float4*)pv = *(float4*)(p40s + g * 40 + j4 * 4);
            #pragma unroll
            for (int u = 0; u < 4; ++u)
                s = fmaf(pv[u], Watt[(j4 * 4 + u) * 40 + f], s);
        }
        phs[it] = s > 0.f ? s : 0.f;
    }
    __syncthreads();

    // ---- attention weight ----
    if (tid < 16) {
        float m = 0.f;
        #pragma unroll
        for (int f4 = 0; f4 < 10; ++f4) {
            float cv[4], ph[4];
            *(float4*)cv = *(const float4*)(ws_cv + (size_t)(blk * 16 + tid) * 40 + f4 * 4);
            *(float4*)ph = *(float4*)(phs + tid * 40 + f4 * 4);
            #pragma unroll
            for (int c = 0; c < 4; ++c) m = fmaf(cv[c], ph[c], m);
        }
        wts[tid] = tanhf(m);
    }
    __syncthreads();

    // ---- cp = [compound_vec | weights * protein_h] ----
    for (int it = tid; it < 1280; it += 256) {
        const int g = it / 80, f = it - g * 80;
        const float v = (f < 40) ? ws_cv[(size_t)(blk * 16 + g) * 40 + f]
                                 : wts[g] * phs[g * 40 + (f - 40)];
        cps[0][g * 84 + f] = v;
    }
    __syncthreads();

    // ---- MLP head ----
    int cb = 0;
    for (int l = 0; l < 2; ++l) {
        for (int it = tid; it < 1280; it += 256) {
            const int g = it / 80, kk = it - g * 80;
            float s = bm[l * 80 + kk];
            #pragma unroll
            for (int j4 = 0; j4 < 20; ++j4) {
                float cv[4];
                *(float4*)cv = *(float4*)(cps[cb] + g * 84 + j4 * 4);
                #pragma unroll
                for (int u = 0; u < 4; ++u)
                    s = fmaf(cv[u], Wm[l * 6400 + (j4 * 4 + u) * 80 + kk], s);
            }
            cps[cb ^ 1][g * 84 + kk] = s > 0.f ? s : 0.f;
        }
        __syncthreads();
        cb ^= 1;
    }
    if (tid < 16) {
        float s = bo[0];
        #pragma unroll
        for (int j4 = 0; j4 < 20; ++j4) {
            float cv[4], wo[4];
            *(float4*)cv = *(float4*)(cps[cb] + tid * 84 + j4 * 4);
            *(float4*)wo = *(const float4*)(Wo + j4 * 4);
            #pragma unroll
            for (int u = 0; u < 4; ++u) s = fmaf(cv[u], wo[u], s);
        }
        out[blk * 16 + tid] = s;
    }
}

extern "C" void kernel_launch(void* const* d_in, const int* in_sizes, int n_in,
                              void* d_out, int out_size, void* d_ws, size_t ws_size,
                              hipStream_t stream) {
    const int*   atoms   = (const int*)d_in[0];
    const float* A       = (const float*)d_in[1];
    const float* A69     = (const float*)d_in[2];
    const float* protein = (const float*)d_in[3];
    const float* emb     = (const float*)d_in[4];
    const float* Wg      = (const float*)d_in[5];
    const float* bg      = (const float*)d_in[6];
    const float* Watt    = (const float*)d_in[7];
    const float* batt    = (const float*)d_in[8];
    const float* W1      = (const float*)d_in[9];
    const float* b1      = (const float*)d_in[10];
    const float* W2      = (const float*)d_in[11];
    const float* b2      = (const float*)d_in[12];
    const float* W3      = (const float*)d_in[13];
    const float* b3      = (const float*)d_in[14];
    const float* Wp      = (const float*)d_in[15];
    const float* bp      = (const float*)d_in[16];
    const float* Wm      = (const float*)d_in[17];
    const float* bm      = (const float*)d_in[18];
    const float* Wo      = (const float*)d_in[19];
    const float* bo      = (const float*)d_in[20];

    float* ws_cv   = (float*)d_ws;                  // [4096][40]
    float* ws_a256 = ws_cv + (size_t)BATCH * 40;    // [4096][256]
    float* outp    = (float*)d_out;

    k_heavy<<<dim3(128 + BATCH), dim3(256), 0, stream>>>(
        atoms, A, A69, emb, Wg, bg, W1, b1, W2, b2, ws_cv, ws_a256);
    k_tail<<<dim3(256), dim3(256), 0, stream>>>(
        protein, W3, b3, Wp, bp, Watt, batt, Wm, bm, Wo, bo, ws_cv, ws_a256, outp);
}